// Round 1
// baseline (2887.829 us; speedup 1.0000x reference)
//
#include <hip/hip_runtime.h>
#include <hip/hip_bf16.h>
#include <math.h>

#define TOKENS 4096
#define DMODEL 2048
#define VOCAB  32000

// GEMM tiling
#define BM 128
#define BN 128
#define BK 64
#define NI 5                 // BN-tiles per block (vocab slice = 640)
#define VSLICE (BN*NI)       // 640
#define VS (VOCAB/VSLICE)    // 50 vocab slices

typedef __attribute__((ext_vector_type(8))) short bf16x8;
typedef __attribute__((ext_vector_type(4))) float f32x4;
typedef __attribute__((ext_vector_type(4))) unsigned int u32x4;

// v_cvt_pk_bf16_f32: no builtin on gfx950 (learn_hip m240) -> inline asm.
// dst.lo16 = bf16_rne(a), dst.hi16 = bf16_rne(b)
__device__ __forceinline__ unsigned int cvt_pk_bf16(float a, float b) {
  unsigned int r;
  asm volatile("v_cvt_pk_bf16_f32 %0, %1, %2" : "=v"(r) : "v"(a), "v"(b));
  return r;
}

// ---------------------------------------------------------------------------
// init: zero s_acc[TOKENS] and the scalar output (harness poisons with 0xAA)
// ---------------------------------------------------------------------------
__global__ void init_kernel(float* __restrict__ s_acc, float* __restrict__ out) {
  int i = blockIdx.x * 256 + threadIdx.x;
  if (i < TOKENS) s_acc[i] = 0.0f;
  if (i == 0) *out = 0.0f;
}

// ---------------------------------------------------------------------------
// target scores: tgt_score[r] = dot(x[r], w[target[r]]) in exact f32
// one wave per row
// ---------------------------------------------------------------------------
__global__ void tgt_kernel(const float* __restrict__ x, const float* __restrict__ w,
                           const int* __restrict__ target, float* __restrict__ tgt_score) {
  int wid  = threadIdx.x >> 6;
  int lane = threadIdx.x & 63;
  int row  = blockIdx.x * 4 + wid;
  if (row >= TOKENS) return;
  int t = target[row];
  const float4* xr = (const float4*)(x + (size_t)row * DMODEL);
  const float4* wr = (const float4*)(w + (size_t)t   * DMODEL);
  float acc = 0.0f;
  #pragma unroll
  for (int i = 0; i < DMODEL/4/64; ++i) {
    float4 a = xr[lane + i*64];
    float4 b = wr[lane + i*64];
    acc += a.x*b.x + a.y*b.y + a.z*b.z + a.w*b.w;
  }
  #pragma unroll
  for (int d = 1; d < 64; d <<= 1) acc += __shfl_xor(acc, d);
  if (lane == 0) tgt_score[row] = acc;
}

// ---------------------------------------------------------------------------
// main fused GEMM + exp-sum kernel (split-bf16 x3 compensated MFMA)
// grid: (VS, TOKENS/BM); block tile BM x BN, 4 waves of 64x64
// LDS planes (bf16, [row][BK] with XOR swizzle): A_hi, A_lo, B_hi, B_lo
// ---------------------------------------------------------------------------
__global__ __launch_bounds__(256, 2)
void gemm_kernel(const float* __restrict__ x, const float* __restrict__ w,
                 float* __restrict__ s_acc) {
  __shared__ unsigned char lds[4 * BM * BK * 2];   // 64 KiB
  const int AH = 0, AL = 16384, BH = 32768, BL = 49152;

  const int tid  = threadIdx.x;
  const int lane = tid & 63;
  const int wid  = tid >> 6;
  const int wr   = wid >> 1;        // wave row (0..1)
  const int wc   = wid & 1;         // wave col (0..1)
  const int l15  = lane & 15;
  const int lq   = lane >> 4;       // 0..3

  const int mbase  = blockIdx.y * BM;
  const int nslice = blockIdx.x * VSLICE;

  float s_part[16];
  #pragma unroll
  for (int i = 0; i < 16; ++i) s_part[i] = 0.0f;

  for (int bn = 0; bn < NI; ++bn) {
    const int nbase = nslice + bn * BN;

    f32x4 acc[4][4];
    #pragma unroll
    for (int m = 0; m < 4; ++m)
      #pragma unroll
      for (int n = 0; n < 4; ++n)
        acc[m][n] = (f32x4){0.f, 0.f, 0.f, 0.f};

    for (int kt = 0; kt < DMODEL / BK; ++kt) {
      const int kb = kt * BK;
      __syncthreads();   // protect LDS against previous iteration's readers

      // ---- stage A (4 tasks) and B (4 tasks); task = 8 consecutive f32 of one row
      #pragma unroll
      for (int i = 0; i < 8; ++i) {
        const int T   = tid + (i & 3) * 256;       // 0..1023
        const int row = T >> 3;
        const int kg  = T & 7;
        const float* src = (i < 4)
            ? (x + (size_t)(mbase + row) * DMODEL + kb + kg * 8)
            : (w + (size_t)(nbase + row) * DMODEL + kb + kg * 8);
        const float4 v0 = ((const float4*)src)[0];
        const float4 v1 = ((const float4*)src)[1];

        // hi = bf16_rne(x); lo = bf16_rne(x - (float)hi)   (x-hi exact, Sterbenz)
        unsigned int h0 = cvt_pk_bf16(v0.x, v0.y);
        unsigned int h1 = cvt_pk_bf16(v0.z, v0.w);
        unsigned int h2 = cvt_pk_bf16(v1.x, v1.y);
        unsigned int h3 = cvt_pk_bf16(v1.z, v1.w);
        float r0 = v0.x - __uint_as_float(h0 << 16);
        float r1 = v0.y - __uint_as_float(h0 & 0xFFFF0000u);
        float r2 = v0.z - __uint_as_float(h1 << 16);
        float r3 = v0.w - __uint_as_float(h1 & 0xFFFF0000u);
        float r4 = v1.x - __uint_as_float(h2 << 16);
        float r5 = v1.y - __uint_as_float(h2 & 0xFFFF0000u);
        float r6 = v1.z - __uint_as_float(h3 << 16);
        float r7 = v1.w - __uint_as_float(h3 & 0xFFFF0000u);
        unsigned int l0 = cvt_pk_bf16(r0, r1);
        unsigned int l1 = cvt_pk_bf16(r2, r3);
        unsigned int l2 = cvt_pk_bf16(r4, r5);
        unsigned int l3 = cvt_pk_bf16(r6, r7);

        // swizzled LDS write ([row][BK] bf16, row stride 128B, 16B-slot XOR)
        const int byteoff = row * 128 + ((kg * 16) ^ ((row & 7) << 4));
        const int hbase = (i < 4) ? AH : BH;
        const int lbase = (i < 4) ? AL : BL;
        *(u32x4*)(lds + hbase + byteoff) = (u32x4){h0, h1, h2, h3};
        *(u32x4*)(lds + lbase + byteoff) = (u32x4){l0, l1, l2, l3};
      }
      __syncthreads();

      // ---- compute: 2 K-halves of 32, 4x4 fragments, 3 MFMA per fragment pair
      #pragma unroll
      for (int kh = 0; kh < 2; ++kh) {
        bf16x8 ah[4], al[4];
        #pragma unroll
        for (int m = 0; m < 4; ++m) {
          const int row = wr * 64 + m * 16 + l15;
          const int bo  = row * 128 + ((kh * 64 + lq * 16) ^ ((row & 7) << 4));
          ah[m] = *(const bf16x8*)(lds + AH + bo);
          al[m] = *(const bf16x8*)(lds + AL + bo);
        }
        #pragma unroll
        for (int n = 0; n < 4; ++n) {
          const int row = wc * 64 + n * 16 + l15;
          const int bo  = row * 128 + ((kh * 64 + lq * 16) ^ ((row & 7) << 4));
          bf16x8 bh = *(const bf16x8*)(lds + BH + bo);
          bf16x8 bl = *(const bf16x8*)(lds + BL + bo);
          #pragma unroll
          for (int m = 0; m < 4; ++m) {
            acc[m][n] = __builtin_amdgcn_mfma_f32_16x16x32_bf16(ah[m], bh, acc[m][n], 0, 0, 0);
            acc[m][n] = __builtin_amdgcn_mfma_f32_16x16x32_bf16(ah[m], bl, acc[m][n], 0, 0, 0);
            acc[m][n] = __builtin_amdgcn_mfma_f32_16x16x32_bf16(al[m], bh, acc[m][n], 0, 0, 0);
          }
        }
      }
    }

    // ---- epilogue: accumulate exp(logit) into per-lane row partials (m == 0 trick)
    #pragma unroll
    for (int m = 0; m < 4; ++m)
      #pragma unroll
      for (int j = 0; j < 4; ++j) {
        float e = 0.0f;
        #pragma unroll
        for (int n = 0; n < 4; ++n) e += __expf(acc[m][n][j]);
        s_part[m * 4 + j] += e;
      }
  }

  // ---- reduce across the 16 lanes sharing each row (cols), then atomicAdd
  #pragma unroll
  for (int i = 0; i < 16; ++i) {
    float v = s_part[i];
    v += __shfl_xor(v, 1);
    v += __shfl_xor(v, 2);
    v += __shfl_xor(v, 4);
    v += __shfl_xor(v, 8);
    s_part[i] = v;
  }
  if (l15 == 0) {
    #pragma unroll
    for (int m = 0; m < 4; ++m)
      #pragma unroll
      for (int j = 0; j < 4; ++j) {
        const int row = mbase + wr * 64 + m * 16 + lq * 4 + j;
        atomicAdd(&s_acc[row], s_part[m * 4 + j]);
      }
  }
}

// ---------------------------------------------------------------------------
// final loss: sum over rows of (log(sum_exp) - tgt_score)   [m == 0]
// ---------------------------------------------------------------------------
__global__ void loss_kernel(const float* __restrict__ s_acc,
                            const float* __restrict__ tgt_score,
                            float* __restrict__ out) {
  int i = blockIdx.x * 256 + threadIdx.x;
  float v = logf(s_acc[i]) - tgt_score[i];
  #pragma unroll
  for (int d = 1; d < 64; d <<= 1) v += __shfl_xor(v, d);
  if ((threadIdx.x & 63) == 0) atomicAdd(out, v);
}

// ---------------------------------------------------------------------------
extern "C" void kernel_launch(void* const* d_in, const int* in_sizes, int n_in,
                              void* d_out, int out_size, void* d_ws, size_t ws_size,
                              hipStream_t stream) {
  const float* x      = (const float*)d_in[0];
  const float* w      = (const float*)d_in[1];
  const int*   target = (const int*)d_in[2];
  float* out = (float*)d_out;

  float* s_acc     = (float*)d_ws;          // [TOKENS]
  float* tgt_score = s_acc + TOKENS;        // [TOKENS]

  init_kernel<<<(TOKENS + 256) / 256, 256, 0, stream>>>(s_acc, out);
  tgt_kernel<<<TOKENS / 4, 256, 0, stream>>>(x, w, target, tgt_score);
  gemm_kernel<<<dim3(VS, TOKENS / BM), 256, 0, stream>>>(x, w, s_acc);
  loss_kernel<<<TOKENS / 256, 256, 0, stream>>>(s_acc, tgt_score, out);
}

// Round 2
// 2000.913 us; speedup vs baseline: 1.4433x; 1.4433x over previous
//
#include <hip/hip_runtime.h>
#include <hip/hip_bf16.h>
#include <math.h>

#define TOKENS 4096
#define DMODEL 2048
#define VOCAB  32000

// GEMM tiling
#define BM 128
#define BN 128
#define BK 64
#define NI 5                 // BN-tiles per block (vocab slice = 640)
#define VSLICE (BN*NI)       // 640
#define VS (VOCAB/VSLICE)    // 50 vocab slices
#define KT (DMODEL/BK)       // 32 k-tiles
#define CHUNK 16384          // one 128x64 bf16 plane tile, bytes

typedef __attribute__((ext_vector_type(8))) short bf16x8;
typedef __attribute__((ext_vector_type(4))) float f32x4;
typedef __attribute__((ext_vector_type(4))) unsigned int u32x4;

// v_cvt_pk_bf16_f32: no builtin on gfx950 (learn_hip m240) -> inline asm.
__device__ __forceinline__ unsigned int cvt_pk_bf16(float a, float b) {
  unsigned int r;
  asm volatile("v_cvt_pk_bf16_f32 %0, %1, %2" : "=v"(r) : "v"(a), "v"(b));
  return r;
}

// async global->LDS, 16B per lane. LDS dest = wave-uniform base + lane*16.
__device__ __forceinline__ void gload16(const unsigned char* g, unsigned char* l) {
  __builtin_amdgcn_global_load_lds((const __attribute__((address_space(1))) unsigned int*)g,
                                   (__attribute__((address_space(3))) unsigned int*)l,
                                   16, 0, 0);
}

// ---------------------------------------------------------------------------
// init: zero s_acc[TOKENS] and the scalar output (harness poisons with 0xAA)
// ---------------------------------------------------------------------------
__global__ void init_kernel(float* __restrict__ s_acc, float* __restrict__ out) {
  int i = blockIdx.x * 256 + threadIdx.x;
  if (i < TOKENS) s_acc[i] = 0.0f;
  if (i == 0) *out = 0.0f;
}

// ---------------------------------------------------------------------------
// target scores: tgt_score[r] = dot(x[r], w[target[r]]) in exact f32
// ---------------------------------------------------------------------------
__global__ void tgt_kernel(const float* __restrict__ x, const float* __restrict__ w,
                           const int* __restrict__ target, float* __restrict__ tgt_score) {
  int wid  = threadIdx.x >> 6;
  int lane = threadIdx.x & 63;
  int row  = blockIdx.x * 4 + wid;
  if (row >= TOKENS) return;
  int t = target[row];
  const float4* xr = (const float4*)(x + (size_t)row * DMODEL);
  const float4* wr = (const float4*)(w + (size_t)t   * DMODEL);
  float acc = 0.0f;
  #pragma unroll
  for (int i = 0; i < DMODEL/4/64; ++i) {
    float4 a = xr[lane + i*64];
    float4 b = wr[lane + i*64];
    acc += a.x*b.x + a.y*b.y + a.z*b.z + a.w*b.w;
  }
  #pragma unroll
  for (int d = 1; d < 64; d <<= 1) acc += __shfl_xor(acc, d);
  if (lane == 0) tgt_score[row] = acc;
}

// ---------------------------------------------------------------------------
// conversion: f32 row-major [R][2048] -> packed swizzled bf16 hi/lo planes.
// Packed layout: chunk c = nblock*32 + kt (16 KB each). Within chunk, byte o:
//   row = o>>7, colbyte = (o&127) ^ ((row&7)<<4)  (XOR bank swizzle baked in)
// so a LINEAR global_load_lds of the chunk reproduces the swizzled LDS tile.
// One thread = one 16B output unit of both planes (8 elems, reads 32B f32).
// ---------------------------------------------------------------------------
__global__ void conv_kernel(const float* __restrict__ src,
                            unsigned char* __restrict__ hp,
                            unsigned char* __restrict__ lp) {
  size_t u = (size_t)blockIdx.x * 256 + threadIdx.x;
  size_t byteoff = u << 4;
  int chunk = (int)(byteoff >> 14);
  int o     = (int)(byteoff & 16383);
  int nb    = chunk >> 5;          // 128-row block
  int kt    = chunk & 31;          // k tile
  int row   = o >> 7;
  int colb  = (o & 127) ^ ((row & 7) << 4);
  const float* s = src + (size_t)(nb * 128 + row) * DMODEL + kt * 64 + (colb >> 1);
  const float4 v0 = ((const float4*)s)[0];
  const float4 v1 = ((const float4*)s)[1];

  unsigned int h0 = cvt_pk_bf16(v0.x, v0.y);
  unsigned int h1 = cvt_pk_bf16(v0.z, v0.w);
  unsigned int h2 = cvt_pk_bf16(v1.x, v1.y);
  unsigned int h3 = cvt_pk_bf16(v1.z, v1.w);
  float r0 = v0.x - __uint_as_float(h0 << 16);
  float r1 = v0.y - __uint_as_float(h0 & 0xFFFF0000u);
  float r2 = v0.z - __uint_as_float(h1 << 16);
  float r3 = v0.w - __uint_as_float(h1 & 0xFFFF0000u);
  float r4 = v1.x - __uint_as_float(h2 << 16);
  float r5 = v1.y - __uint_as_float(h2 & 0xFFFF0000u);
  float r6 = v1.z - __uint_as_float(h3 << 16);
  float r7 = v1.w - __uint_as_float(h3 & 0xFFFF0000u);
  unsigned int l0 = cvt_pk_bf16(r0, r1);
  unsigned int l1 = cvt_pk_bf16(r2, r3);
  unsigned int l2 = cvt_pk_bf16(r4, r5);
  unsigned int l3 = cvt_pk_bf16(r6, r7);

  *(u32x4*)(hp + byteoff) = (u32x4){h0, h1, h2, h3};
  *(u32x4*)(lp + byteoff) = (u32x4){l0, l1, l2, l3};
}

// ---------------------------------------------------------------------------
// main GEMM + exp-sum, packed-plane inputs, global_load_lds staging.
// grid: 1600 blocks (XCD-chunk-swizzled -> (vocab slice, m tile))
// ---------------------------------------------------------------------------
__global__ __launch_bounds__(256, 2)
void gemm_packed(const unsigned char* __restrict__ xh, const unsigned char* __restrict__ xl,
                 const unsigned char* __restrict__ wh, const unsigned char* __restrict__ wl,
                 float* __restrict__ s_acc) {
  __shared__ unsigned char lds[4 * CHUNK];   // 64 KiB: AH | AL | BH | BL
  const int AH = 0, AL = 16384, BH = 32768, BL = 49152;

  const int tid  = threadIdx.x;
  const int lane = tid & 63;
  const int wid  = tid >> 6;
  const int wr   = wid >> 1;
  const int wc   = wid & 1;
  const int l15  = lane & 15;
  const int lq   = lane >> 4;

  // bijective XCD-chunked swizzle: 1600 = 8 XCD * 200
  const int wg  = blockIdx.x;
  const int swz = (wg & 7) * 200 + (wg >> 3);
  const int v   = swz >> 5;        // vocab slice 0..49
  const int mb  = swz & 31;        // m tile 0..31
  const int mbase = mb * BM;

  float s_part[16];
  #pragma unroll
  for (int i = 0; i < 16; ++i) s_part[i] = 0.0f;

  const int toff = (wid << 12) + (lane << 4);   // wave-linear staging offset

  for (int bn = 0; bn < NI; ++bn) {
    const int nb = v * NI + bn;    // 128-row vocab block, 0..249

    f32x4 acc[4][4];
    #pragma unroll
    for (int m = 0; m < 4; ++m)
      #pragma unroll
      for (int n = 0; n < 4; ++n)
        acc[m][n] = (f32x4){0.f, 0.f, 0.f, 0.f};

    for (int kt = 0; kt < KT; ++kt) {
      __syncthreads();   // prior readers done before overwriting LDS

      const unsigned char* sa = xh + ((size_t)((mb << 5) + kt) << 14);
      const unsigned char* sb = xl + ((size_t)((mb << 5) + kt) << 14);
      const unsigned char* sc = wh + ((size_t)((nb << 5) + kt) << 14);
      const unsigned char* sd = wl + ((size_t)((nb << 5) + kt) << 14);
      #pragma unroll
      for (int i = 0; i < 4; ++i) {
        const int off = toff + (i << 10);
        gload16(sa + off, lds + AH + off);
        gload16(sb + off, lds + AL + off);
        gload16(sc + off, lds + BH + off);
        gload16(sd + off, lds + BL + off);
      }
      __syncthreads();   // drains vmcnt(0): staged tiles visible

      // ---- compute: 2 K-halves of 32, 4x4 fragments, 3 MFMA per pair
      #pragma unroll
      for (int kh = 0; kh < 2; ++kh) {
        bf16x8 ah[4], al[4];
        #pragma unroll
        for (int m = 0; m < 4; ++m) {
          const int row = wr * 64 + m * 16 + l15;
          const int bo  = row * 128 + ((kh * 64 + lq * 16) ^ ((row & 7) << 4));
          ah[m] = *(const bf16x8*)(lds + AH + bo);
          al[m] = *(const bf16x8*)(lds + AL + bo);
        }
        #pragma unroll
        for (int n = 0; n < 4; ++n) {
          const int row = wc * 64 + n * 16 + l15;
          const int bo  = row * 128 + ((kh * 64 + lq * 16) ^ ((row & 7) << 4));
          bf16x8 bh = *(const bf16x8*)(lds + BH + bo);
          bf16x8 bl = *(const bf16x8*)(lds + BL + bo);
          #pragma unroll
          for (int m = 0; m < 4; ++m) {
            acc[m][n] = __builtin_amdgcn_mfma_f32_16x16x32_bf16(ah[m], bh, acc[m][n], 0, 0, 0);
            acc[m][n] = __builtin_amdgcn_mfma_f32_16x16x32_bf16(ah[m], bl, acc[m][n], 0, 0, 0);
            acc[m][n] = __builtin_amdgcn_mfma_f32_16x16x32_bf16(al[m], bh, acc[m][n], 0, 0, 0);
          }
        }
      }
    }

    // ---- epilogue: accumulate exp(logit) per row (max term == 0 trick)
    #pragma unroll
    for (int m = 0; m < 4; ++m)
      #pragma unroll
      for (int j = 0; j < 4; ++j) {
        float e = 0.0f;
        #pragma unroll
        for (int n = 0; n < 4; ++n) e += __expf(acc[m][n][j]);
        s_part[m * 4 + j] += e;
      }
  }

  // ---- reduce across the 16 lanes sharing each row, then atomicAdd
  #pragma unroll
  for (int i = 0; i < 16; ++i) {
    float vv = s_part[i];
    vv += __shfl_xor(vv, 1);
    vv += __shfl_xor(vv, 2);
    vv += __shfl_xor(vv, 4);
    vv += __shfl_xor(vv, 8);
    s_part[i] = vv;
  }
  if (l15 == 0) {
    #pragma unroll
    for (int m = 0; m < 4; ++m)
      #pragma unroll
      for (int j = 0; j < 4; ++j) {
        const int row = mbase + wr * 64 + m * 16 + lq * 4 + j;
        atomicAdd(&s_acc[row], s_part[m * 4 + j]);
      }
  }
}

// ---------------------------------------------------------------------------
// fallback GEMM (round-1 reg-staging version) if ws_size can't hold planes
// ---------------------------------------------------------------------------
__global__ __launch_bounds__(256, 2)
void gemm_fallback(const float* __restrict__ x, const float* __restrict__ w,
                   float* __restrict__ s_acc) {
  __shared__ unsigned char lds[4 * BM * BK * 2];
  const int AH = 0, AL = 16384, BH = 32768, BL = 49152;
  const int tid  = threadIdx.x;
  const int lane = tid & 63;
  const int wid  = tid >> 6;
  const int wr   = wid >> 1;
  const int wc   = wid & 1;
  const int l15  = lane & 15;
  const int lq   = lane >> 4;
  const int mbase  = blockIdx.y * BM;
  const int nslice = blockIdx.x * VSLICE;

  float s_part[16];
  #pragma unroll
  for (int i = 0; i < 16; ++i) s_part[i] = 0.0f;

  for (int bn = 0; bn < NI; ++bn) {
    const int nbase = nslice + bn * BN;
    f32x4 acc[4][4];
    #pragma unroll
    for (int m = 0; m < 4; ++m)
      #pragma unroll
      for (int n = 0; n < 4; ++n)
        acc[m][n] = (f32x4){0.f, 0.f, 0.f, 0.f};

    for (int kt = 0; kt < KT; ++kt) {
      const int kb = kt * BK;
      __syncthreads();
      #pragma unroll
      for (int i = 0; i < 8; ++i) {
        const int T   = tid + (i & 3) * 256;
        const int row = T >> 3;
        const int kg  = T & 7;
        const float* src = (i < 4)
            ? (x + (size_t)(mbase + row) * DMODEL + kb + kg * 8)
            : (w + (size_t)(nbase + row) * DMODEL + kb + kg * 8);
        const float4 v0 = ((const float4*)src)[0];
        const float4 v1 = ((const float4*)src)[1];
        unsigned int h0 = cvt_pk_bf16(v0.x, v0.y);
        unsigned int h1 = cvt_pk_bf16(v0.z, v0.w);
        unsigned int h2 = cvt_pk_bf16(v1.x, v1.y);
        unsigned int h3 = cvt_pk_bf16(v1.z, v1.w);
        float r0 = v0.x - __uint_as_float(h0 << 16);
        float r1 = v0.y - __uint_as_float(h0 & 0xFFFF0000u);
        float r2 = v0.z - __uint_as_float(h1 << 16);
        float r3 = v0.w - __uint_as_float(h1 & 0xFFFF0000u);
        float r4 = v1.x - __uint_as_float(h2 << 16);
        float r5 = v1.y - __uint_as_float(h2 & 0xFFFF0000u);
        float r6 = v1.z - __uint_as_float(h3 << 16);
        float r7 = v1.w - __uint_as_float(h3 & 0xFFFF0000u);
        unsigned int l0 = cvt_pk_bf16(r0, r1);
        unsigned int l1 = cvt_pk_bf16(r2, r3);
        unsigned int l2 = cvt_pk_bf16(r4, r5);
        unsigned int l3 = cvt_pk_bf16(r6, r7);
        const int byteoff = row * 128 + ((kg * 16) ^ ((row & 7) << 4));
        const int hbase = (i < 4) ? AH : BH;
        const int lbase = (i < 4) ? AL : BL;
        *(u32x4*)(lds + hbase + byteoff) = (u32x4){h0, h1, h2, h3};
        *(u32x4*)(lds + lbase + byteoff) = (u32x4){l0, l1, l2, l3};
      }
      __syncthreads();

      #pragma unroll
      for (int kh = 0; kh < 2; ++kh) {
        bf16x8 ah[4], al[4];
        #pragma unroll
        for (int m = 0; m < 4; ++m) {
          const int row = wr * 64 + m * 16 + l15;
          const int bo  = row * 128 + ((kh * 64 + lq * 16) ^ ((row & 7) << 4));
          ah[m] = *(const bf16x8*)(lds + AH + bo);
          al[m] = *(const bf16x8*)(lds + AL + bo);
        }
        #pragma unroll
        for (int n = 0; n < 4; ++n) {
          const int row = wc * 64 + n * 16 + l15;
          const int bo  = row * 128 + ((kh * 64 + lq * 16) ^ ((row & 7) << 4));
          bf16x8 bh = *(const bf16x8*)(lds + BH + bo);
          bf16x8 bl = *(const bf16x8*)(lds + BL + bo);
          #pragma unroll
          for (int m = 0; m < 4; ++m) {
            acc[m][n] = __builtin_amdgcn_mfma_f32_16x16x32_bf16(ah[m], bh, acc[m][n], 0, 0, 0);
            acc[m][n] = __builtin_amdgcn_mfma_f32_16x16x32_bf16(ah[m], bl, acc[m][n], 0, 0, 0);
            acc[m][n] = __builtin_amdgcn_mfma_f32_16x16x32_bf16(al[m], bh, acc[m][n], 0, 0, 0);
          }
        }
      }
    }

    #pragma unroll
    for (int m = 0; m < 4; ++m)
      #pragma unroll
      for (int j = 0; j < 4; ++j) {
        float e = 0.0f;
        #pragma unroll
        for (int n = 0; n < 4; ++n) e += __expf(acc[m][n][j]);
        s_part[m * 4 + j] += e;
      }
  }

  #pragma unroll
  for (int i = 0; i < 16; ++i) {
    float vv = s_part[i];
    vv += __shfl_xor(vv, 1);
    vv += __shfl_xor(vv, 2);
    vv += __shfl_xor(vv, 4);
    vv += __shfl_xor(vv, 8);
    s_part[i] = vv;
  }
  if (l15 == 0) {
    #pragma unroll
    for (int m = 0; m < 4; ++m)
      #pragma unroll
      for (int j = 0; j < 4; ++j) {
        const int row = mbase + wr * 64 + m * 16 + lq * 4 + j;
        atomicAdd(&s_acc[row], s_part[m * 4 + j]);
      }
  }
}

// ---------------------------------------------------------------------------
// final loss: sum over rows of (log(sum_exp) - tgt_score)
// ---------------------------------------------------------------------------
__global__ void loss_kernel(const float* __restrict__ s_acc,
                            const float* __restrict__ tgt_score,
                            float* __restrict__ out) {
  int i = blockIdx.x * 256 + threadIdx.x;
  float v = logf(s_acc[i]) - tgt_score[i];
  #pragma unroll
  for (int d = 1; d < 64; d <<= 1) v += __shfl_xor(v, d);
  if ((threadIdx.x & 63) == 0) atomicAdd(out, v);
}

// ---------------------------------------------------------------------------
extern "C" void kernel_launch(void* const* d_in, const int* in_sizes, int n_in,
                              void* d_out, int out_size, void* d_ws, size_t ws_size,
                              hipStream_t stream) {
  const float* x      = (const float*)d_in[0];
  const float* w      = (const float*)d_in[1];
  const int*   target = (const int*)d_in[2];
  float* out = (float*)d_out;

  float* s_acc     = (float*)d_ws;          // [TOKENS]
  float* tgt_score = s_acc + TOKENS;        // [TOKENS]
  unsigned char* base = (unsigned char*)(tgt_score + TOKENS);
  const size_t XPLANE = (size_t)TOKENS * DMODEL * 2;   // 16,777,216 B
  const size_t WPLANE = (size_t)VOCAB  * DMODEL * 2;   // 131,072,000 B
  unsigned char* xh = base;
  unsigned char* xl = xh + XPLANE;
  unsigned char* wh = xl + XPLANE;
  unsigned char* wl = wh + WPLANE;
  const size_t needed = (size_t)2 * TOKENS * 4 + 2 * XPLANE + 2 * WPLANE;

  init_kernel<<<(TOKENS + 255) / 256, 256, 0, stream>>>(s_acc, out);
  tgt_kernel<<<TOKENS / 4, 256, 0, stream>>>(x, w, target, tgt_score);

  if (ws_size >= needed) {
    conv_kernel<<<(int)(XPLANE / 16 / 256), 256, 0, stream>>>(x, xh, xl);
    conv_kernel<<<(int)(WPLANE / 16 / 256), 256, 0, stream>>>(w, wh, wl);
    gemm_packed<<<VS * (TOKENS / BM), 256, 0, stream>>>(xh, xl, wh, wl, s_acc);
  } else {
    gemm_fallback<<<dim3(VS, TOKENS / BM), 256, 0, stream>>>(x, w, s_acc);
  }

  loss_kernel<<<TOKENS / 256, 256, 0, stream>>>(s_acc, tgt_score, out);
}

// Round 3
// 1494.664 us; speedup vs baseline: 1.9321x; 1.3387x over previous
//
#include <hip/hip_runtime.h>
#include <hip/hip_bf16.h>
#include <math.h>

#define TOKENS 4096
#define DMODEL 2048
#define VOCAB  32000

// ---- packed 8-wave geometry (new) ----
#define BM2 256
#define BK2 32
#define NKT 64               // DMODEL/BK2
#define MT  16               // TOKENS/BM2
#define NT  125              // VOCAB/BM2  -> grid 2000 = 8*250

// ---- legacy fallback geometry ----
#define BM 128
#define BN 128
#define BK 64
#define NI 5
#define VSLICE (BN*NI)
#define VS (VOCAB/VSLICE)
#define KT (DMODEL/BK)

typedef __attribute__((ext_vector_type(8))) short bf16x8;
typedef __attribute__((ext_vector_type(4))) float f32x4;
typedef __attribute__((ext_vector_type(4))) unsigned int u32x4;

__device__ __forceinline__ unsigned int cvt_pk_bf16(float a, float b) {
  unsigned int r;
  asm volatile("v_cvt_pk_bf16_f32 %0, %1, %2" : "=v"(r) : "v"(a), "v"(b));
  return r;
}

__device__ __forceinline__ void gload16(const unsigned char* g, unsigned char* l) {
  __builtin_amdgcn_global_load_lds((const __attribute__((address_space(1))) unsigned int*)g,
                                   (__attribute__((address_space(3))) unsigned int*)l,
                                   16, 0, 0);
}

// ---------------------------------------------------------------------------
__global__ void init_kernel(float* __restrict__ s_acc, float* __restrict__ out) {
  int i = blockIdx.x * 256 + threadIdx.x;
  if (i < TOKENS) s_acc[i] = 0.0f;
  if (i == 0) *out = 0.0f;
}

// ---------------------------------------------------------------------------
__global__ void tgt_kernel(const float* __restrict__ x, const float* __restrict__ w,
                           const int* __restrict__ target, float* __restrict__ tgt_score) {
  int wid  = threadIdx.x >> 6;
  int lane = threadIdx.x & 63;
  int row  = blockIdx.x * 4 + wid;
  if (row >= TOKENS) return;
  int t = target[row];
  const float4* xr = (const float4*)(x + (size_t)row * DMODEL);
  const float4* wr = (const float4*)(w + (size_t)t   * DMODEL);
  float acc = 0.0f;
  #pragma unroll
  for (int i = 0; i < DMODEL/4/64; ++i) {
    float4 a = xr[lane + i*64];
    float4 b = wr[lane + i*64];
    acc += a.x*b.x + a.y*b.y + a.z*b.z + a.w*b.w;
  }
  #pragma unroll
  for (int d = 1; d < 64; d <<= 1) acc += __shfl_xor(acc, d);
  if (lane == 0) tgt_score[row] = acc;
}

// ---------------------------------------------------------------------------
// conversion: f32 [R][2048] -> packed swizzled bf16 hi/lo planes for BK2=32.
// chunk = rowblock(256)*64 + ktile(32 cols); 16KB each. byte o in chunk:
//   row = o>>6, colb = (o&63) ^ (((row>>1)&3)<<4)   (2-way-free bank swizzle)
// Linear global_load_lds of a chunk reproduces the swizzled LDS image.
// ---------------------------------------------------------------------------
__global__ void conv_kernel(const float* __restrict__ src,
                            unsigned char* __restrict__ hp,
                            unsigned char* __restrict__ lp) {
  size_t u = (size_t)blockIdx.x * 256 + threadIdx.x;
  size_t byteoff = u << 4;
  int chunk = (int)(byteoff >> 14);
  int o     = (int)(byteoff & 16383);
  int rb    = chunk >> 6;
  int kt    = chunk & 63;
  int row   = o >> 6;
  int colb  = (o & 63) ^ (((row >> 1) & 3) << 4);
  const float* s = src + (size_t)(rb * 256 + row) * DMODEL + kt * 32 + (colb >> 1);
  const float4 v0 = ((const float4*)s)[0];
  const float4 v1 = ((const float4*)s)[1];

  unsigned int h0 = cvt_pk_bf16(v0.x, v0.y);
  unsigned int h1 = cvt_pk_bf16(v0.z, v0.w);
  unsigned int h2 = cvt_pk_bf16(v1.x, v1.y);
  unsigned int h3 = cvt_pk_bf16(v1.z, v1.w);
  float r0 = v0.x - __uint_as_float(h0 << 16);
  float r1 = v0.y - __uint_as_float(h0 & 0xFFFF0000u);
  float r2 = v0.z - __uint_as_float(h1 << 16);
  float r3 = v0.w - __uint_as_float(h1 & 0xFFFF0000u);
  float r4 = v1.x - __uint_as_float(h2 << 16);
  float r5 = v1.y - __uint_as_float(h2 & 0xFFFF0000u);
  float r6 = v1.z - __uint_as_float(h3 << 16);
  float r7 = v1.w - __uint_as_float(h3 & 0xFFFF0000u);
  unsigned int l0 = cvt_pk_bf16(r0, r1);
  unsigned int l1 = cvt_pk_bf16(r2, r3);
  unsigned int l2 = cvt_pk_bf16(r4, r5);
  unsigned int l3 = cvt_pk_bf16(r6, r7);

  *(u32x4*)(hp + byteoff) = (u32x4){h0, h1, h2, h3};
  *(u32x4*)(lp + byteoff) = (u32x4){l0, l1, l2, l3};
}

// ---------------------------------------------------------------------------
// K-tile body: read bufR, stage tile ktn into bufW (if in range).
// One barrier per tile; vmcnt(0) waits only for loads issued a FULL tile ago.
// ---------------------------------------------------------------------------
template<int BUFR, int BUFW>
__device__ __forceinline__ void ktile(
    unsigned char* lds,
    const unsigned char* __restrict__ xh, const unsigned char* __restrict__ xl,
    const unsigned char* __restrict__ wh, const unsigned char* __restrict__ wl,
    size_t abase, size_t bbase, int ktn, int st0, int st1,
    int wr, int wc, int laneoff, f32x4 (&acc)[8][4])
{
  asm volatile("s_waitcnt vmcnt(0)" ::: "memory");   // tile-t loads landed (issued 1 tile ago)
  __builtin_amdgcn_s_barrier();                      // all waves done reading bufW's old data
  __builtin_amdgcn_sched_barrier(0);

  if (ktn < NKT) {                                   // issue next tile's 8 loads EARLY
    const size_t ca = abase + ((size_t)ktn << 14);
    const size_t cb = bbase + ((size_t)ktn << 14);
    gload16(xh + ca + st0, lds + BUFW + st0);
    gload16(xh + ca + st1, lds + BUFW + st1);
    gload16(xl + ca + st0, lds + BUFW + 16384 + st0);
    gload16(xl + ca + st1, lds + BUFW + 16384 + st1);
    gload16(wh + cb + st0, lds + BUFW + 32768 + st0);
    gload16(wh + cb + st1, lds + BUFW + 32768 + st1);
    gload16(wl + cb + st0, lds + BUFW + 49152 + st0);
    gload16(wl + cb + st1, lds + BUFW + 49152 + st1);
  }
  __builtin_amdgcn_sched_barrier(0);

  bf16x8 bh[4], bl[4];
  #pragma unroll
  for (int n = 0; n < 4; ++n) {
    const int bo = BUFR + 32768 + wc * 4096 + n * 1024 + laneoff;
    bh[n] = *(const bf16x8*)(lds + bo);
    bl[n] = *(const bf16x8*)(lds + bo + 16384);
  }
  #pragma unroll
  for (int p = 0; p < 4; ++p) {
    bf16x8 ah[2], al[2];
    #pragma unroll
    for (int mm = 0; mm < 2; ++mm) {
      const int ao = BUFR + wr * 8192 + (p * 2 + mm) * 1024 + laneoff;
      ah[mm] = *(const bf16x8*)(lds + ao);
      al[mm] = *(const bf16x8*)(lds + ao + 16384);
    }
    __builtin_amdgcn_s_setprio(1);
    #pragma unroll
    for (int mm = 0; mm < 2; ++mm)
      #pragma unroll
      for (int n = 0; n < 4; ++n) {
        acc[p*2+mm][n] = __builtin_amdgcn_mfma_f32_16x16x32_bf16(ah[mm], bh[n], acc[p*2+mm][n], 0, 0, 0);
        acc[p*2+mm][n] = __builtin_amdgcn_mfma_f32_16x16x32_bf16(ah[mm], bl[n], acc[p*2+mm][n], 0, 0, 0);
        acc[p*2+mm][n] = __builtin_amdgcn_mfma_f32_16x16x32_bf16(al[mm], bh[n], acc[p*2+mm][n], 0, 0, 0);
      }
    __builtin_amdgcn_s_setprio(0);
  }
}

// ---------------------------------------------------------------------------
// 256x256 tile, BK=32, 8 waves, dbuf 128KB LDS, counted-latency pipeline.
// ---------------------------------------------------------------------------
__global__ __launch_bounds__(512, 2)
void gemm_packed8(const unsigned char* __restrict__ xh, const unsigned char* __restrict__ xl,
                  const unsigned char* __restrict__ wh, const unsigned char* __restrict__ wl,
                  float* __restrict__ s_acc)
{
  __shared__ unsigned char lds[131072];

  const int tid  = threadIdx.x;
  const int lane = tid & 63;
  const int wid  = tid >> 6;
  const int wr   = wid >> 2;        // 0..1
  const int wc   = wid & 3;         // 0..3
  const int l15  = lane & 15;
  const int lq   = lane >> 4;

  // bijective XCD swizzle: 2000 = 8 * 250; within an XCD, m-tile fastest
  const int wg    = blockIdx.x;
  const int swz   = (wg & 7) * 250 + (wg >> 3);
  const int vtile = swz >> 4;       // 0..124 (shares W panel across 16 m-tiles)
  const int mtile = swz & 15;       // 0..15

  const size_t abase = ((size_t)(mtile * NKT)) << 14;
  const size_t bbase = ((size_t)(vtile * NKT)) << 14;
  const int st0 = tid << 4;
  const int st1 = 8192 + (tid << 4);
  const int laneoff = l15 * 64 + ((lq * 16) ^ (((l15 >> 1) & 3) << 4));

  f32x4 acc[8][4];
  #pragma unroll
  for (int m = 0; m < 8; ++m)
    #pragma unroll
    for (int n = 0; n < 4; ++n)
      acc[m][n] = (f32x4){0.f, 0.f, 0.f, 0.f};

  // prologue: tile 0 -> buf0
  gload16(xh + abase + st0, lds + st0);
  gload16(xh + abase + st1, lds + st1);
  gload16(xl + abase + st0, lds + 16384 + st0);
  gload16(xl + abase + st1, lds + 16384 + st1);
  gload16(wh + bbase + st0, lds + 32768 + st0);
  gload16(wh + bbase + st1, lds + 32768 + st1);
  gload16(wl + bbase + st0, lds + 49152 + st0);
  gload16(wl + bbase + st1, lds + 49152 + st1);

  for (int t = 0; t < NKT; t += 2) {
    ktile<0, 65536>(lds, xh, xl, wh, wl, abase, bbase, t + 1, st0, st1, wr, wc, laneoff, acc);
    ktile<65536, 0>(lds, xh, xl, wh, wl, abase, bbase, t + 2, st0, st1, wr, wc, laneoff, acc);
  }
  // drain stray DMA before LDS is handed to the next workgroup
  asm volatile("s_waitcnt vmcnt(0)" ::: "memory");

  // epilogue: exp-sum per row (max term == 0), reduce over 16 col-lanes
  #pragma unroll
  for (int m = 0; m < 8; ++m) {
    #pragma unroll
    for (int j = 0; j < 4; ++j) {
      float e = 0.f;
      #pragma unroll
      for (int n = 0; n < 4; ++n) e += __expf(acc[m][n][j]);
      e += __shfl_xor(e, 1);
      e += __shfl_xor(e, 2);
      e += __shfl_xor(e, 4);
      e += __shfl_xor(e, 8);
      if (l15 == 0)
        atomicAdd(&s_acc[mtile * BM2 + wr * 128 + m * 16 + lq * 4 + j], e);
    }
  }
}

// ---------------------------------------------------------------------------
// fallback (round-1 reg-staging version) if ws can't hold the planes
// ---------------------------------------------------------------------------
__global__ __launch_bounds__(256, 2)
void gemm_fallback(const float* __restrict__ x, const float* __restrict__ w,
                   float* __restrict__ s_acc) {
  __shared__ unsigned char lds[4 * BM * BK * 2];
  const int AH = 0, AL = 16384, BH = 32768, BL = 49152;
  const int tid  = threadIdx.x;
  const int lane = tid & 63;
  const int wid  = tid >> 6;
  const int wrr  = wid >> 1;
  const int wcc  = wid & 1;
  const int l15  = lane & 15;
  const int lq   = lane >> 4;
  const int mbase  = blockIdx.y * BM;
  const int nslice = blockIdx.x * VSLICE;

  float s_part[16];
  #pragma unroll
  for (int i = 0; i < 16; ++i) s_part[i] = 0.0f;

  for (int bn = 0; bn < NI; ++bn) {
    const int nbase = nslice + bn * BN;
    f32x4 acc[4][4];
    #pragma unroll
    for (int m = 0; m < 4; ++m)
      #pragma unroll
      for (int n = 0; n < 4; ++n)
        acc[m][n] = (f32x4){0.f, 0.f, 0.f, 0.f};

    for (int kt = 0; kt < KT; ++kt) {
      const int kb = kt * BK;
      __syncthreads();
      #pragma unroll
      for (int i = 0; i < 8; ++i) {
        const int T   = tid + (i & 3) * 256;
        const int row = T >> 3;
        const int kg  = T & 7;
        const float* src = (i < 4)
            ? (x + (size_t)(mbase + row) * DMODEL + kb + kg * 8)
            : (w + (size_t)(nbase + row) * DMODEL + kb + kg * 8);
        const float4 v0 = ((const float4*)src)[0];
        const float4 v1 = ((const float4*)src)[1];
        unsigned int h0 = cvt_pk_bf16(v0.x, v0.y);
        unsigned int h1 = cvt_pk_bf16(v0.z, v0.w);
        unsigned int h2 = cvt_pk_bf16(v1.x, v1.y);
        unsigned int h3 = cvt_pk_bf16(v1.z, v1.w);
        float r0 = v0.x - __uint_as_float(h0 << 16);
        float r1 = v0.y - __uint_as_float(h0 & 0xFFFF0000u);
        float r2 = v0.z - __uint_as_float(h1 << 16);
        float r3 = v0.w - __uint_as_float(h1 & 0xFFFF0000u);
        float r4 = v1.x - __uint_as_float(h2 << 16);
        float r5 = v1.y - __uint_as_float(h2 & 0xFFFF0000u);
        float r6 = v1.z - __uint_as_float(h3 << 16);
        float r7 = v1.w - __uint_as_float(h3 & 0xFFFF0000u);
        unsigned int l0 = cvt_pk_bf16(r0, r1);
        unsigned int l1 = cvt_pk_bf16(r2, r3);
        unsigned int l2 = cvt_pk_bf16(r4, r5);
        unsigned int l3 = cvt_pk_bf16(r6, r7);
        const int byteoff = row * 128 + ((kg * 16) ^ ((row & 7) << 4));
        const int hbase = (i < 4) ? AH : BH;
        const int lbase = (i < 4) ? AL : BL;
        *(u32x4*)(lds + hbase + byteoff) = (u32x4){h0, h1, h2, h3};
        *(u32x4*)(lds + lbase + byteoff) = (u32x4){l0, l1, l2, l3};
      }
      __syncthreads();

      #pragma unroll
      for (int kh = 0; kh < 2; ++kh) {
        bf16x8 ah[4], al[4];
        #pragma unroll
        for (int m = 0; m < 4; ++m) {
          const int row = wrr * 64 + m * 16 + l15;
          const int bo  = row * 128 + ((kh * 64 + lq * 16) ^ ((row & 7) << 4));
          ah[m] = *(const bf16x8*)(lds + AH + bo);
          al[m] = *(const bf16x8*)(lds + AL + bo);
        }
        #pragma unroll
        for (int n = 0; n < 4; ++n) {
          const int row = wcc * 64 + n * 16 + l15;
          const int bo  = row * 128 + ((kh * 64 + lq * 16) ^ ((row & 7) << 4));
          bf16x8 bh = *(const bf16x8*)(lds + BH + bo);
          bf16x8 bl = *(const bf16x8*)(lds + BL + bo);
          #pragma unroll
          for (int m = 0; m < 4; ++m) {
            acc[m][n] = __builtin_amdgcn_mfma_f32_16x16x32_bf16(ah[m], bh, acc[m][n], 0, 0, 0);
            acc[m][n] = __builtin_amdgcn_mfma_f32_16x16x32_bf16(ah[m], bl, acc[m][n], 0, 0, 0);
            acc[m][n] = __builtin_amdgcn_mfma_f32_16x16x32_bf16(al[m], bh, acc[m][n], 0, 0, 0);
          }
        }
      }
    }

    #pragma unroll
    for (int m = 0; m < 4; ++m)
      #pragma unroll
      for (int j = 0; j < 4; ++j) {
        float e = 0.0f;
        #pragma unroll
        for (int n = 0; n < 4; ++n) e += __expf(acc[m][n][j]);
        s_part[m * 4 + j] += e;
      }
  }

  #pragma unroll
  for (int i = 0; i < 16; ++i) {
    float vv = s_part[i];
    vv += __shfl_xor(vv, 1);
    vv += __shfl_xor(vv, 2);
    vv += __shfl_xor(vv, 4);
    vv += __shfl_xor(vv, 8);
    s_part[i] = vv;
  }
  if (l15 == 0) {
    #pragma unroll
    for (int m = 0; m < 4; ++m)
      #pragma unroll
      for (int j = 0; j < 4; ++j) {
        const int row = mbase + wrr * 64 + m * 16 + lq * 4 + j;
        atomicAdd(&s_acc[row], s_part[m * 4 + j]);
      }
  }
}

// ---------------------------------------------------------------------------
__global__ void loss_kernel(const float* __restrict__ s_acc,
                            const float* __restrict__ tgt_score,
                            float* __restrict__ out) {
  int i = blockIdx.x * 256 + threadIdx.x;
  float v = logf(s_acc[i]) - tgt_score[i];
  #pragma unroll
  for (int d = 1; d < 64; d <<= 1) v += __shfl_xor(v, d);
  if ((threadIdx.x & 63) == 0) atomicAdd(out, v);
}

// ---------------------------------------------------------------------------
extern "C" void kernel_launch(void* const* d_in, const int* in_sizes, int n_in,
                              void* d_out, int out_size, void* d_ws, size_t ws_size,
                              hipStream_t stream) {
  const float* x      = (const float*)d_in[0];
  const float* w      = (const float*)d_in[1];
  const int*   target = (const int*)d_in[2];
  float* out = (float*)d_out;

  float* s_acc     = (float*)d_ws;
  float* tgt_score = s_acc + TOKENS;
  unsigned char* base = (unsigned char*)(tgt_score + TOKENS);
  const size_t XPLANE = (size_t)TOKENS * DMODEL * 2;   // 16,777,216 B
  const size_t WPLANE = (size_t)VOCAB  * DMODEL * 2;   // 131,072,000 B
  unsigned char* xh = base;
  unsigned char* xl = xh + XPLANE;
  unsigned char* wh = xl + XPLANE;
  unsigned char* wl = wh + WPLANE;
  const size_t needed = (size_t)2 * TOKENS * 4 + 2 * XPLANE + 2 * WPLANE;

  init_kernel<<<(TOKENS + 255) / 256, 256, 0, stream>>>(s_acc, out);
  tgt_kernel<<<TOKENS / 4, 256, 0, stream>>>(x, w, target, tgt_score);

  if (ws_size >= needed) {
    conv_kernel<<<(int)(XPLANE / 16 / 256), 256, 0, stream>>>(x, xh, xl);
    conv_kernel<<<(int)(WPLANE / 16 / 256), 256, 0, stream>>>(w, wh, wl);
    gemm_packed8<<<MT * NT, 512, 0, stream>>>(xh, xl, wh, wl, s_acc);
  } else {
    gemm_fallback<<<dim3(VS, TOKENS / BM), 256, 0, stream>>>(x, w, s_acc);
  }

  loss_kernel<<<TOKENS / 256, 256, 0, stream>>>(s_acc, tgt_score, out);
}